// Round 14
// baseline (146.282 us; speedup 1.0000x reference)
//
#include <hip/hip_runtime.h>
#include <math.h>

// Problem constants
#define KS    11
#define H     512
#define W     512
#define OH    502
#define OW    502
#define NPLANES 48
#define TOTAL_OUT (NPLANES * OH * OW)   // 12,096,192

// Round 14: BARRIER-FREE wave-private strips.
// Each wave owns 64 input cols -> 54 output cols, and a private LDS slice for the
// vconv->hconv transpose. Same-wave LDS ops are ordered by HW + lgkmcnt -> the main
// loop has ZERO __syncthreads (r13 analysis: ~2.2x stall inflation from 12 barriers).
#define TH      4
#define IROWS   (TH + KS - 1)     // 14 input rows in the register window
#define SCOLS   64                // input cols per wave strip (= lanes)
#define SOUT    54                // valid output cols per strip (64 - 10 halo)
#define LVWS    67                // slice row length in float2 (>= 52+13+1; stride 134 words == 6 mod 32)
#define NSTRIPS 10                // 10 x 54 = 540 >= 502
#define NTHREADS 512
#define WCHUNK  32                // output rows per wave (8 iters x TH)
#define NITER   8

typedef float v2f __attribute__((ext_vector_type(2)));

__global__ void zero_out_kernel(float* out) { out[0] = 0.0f; }

__device__ __forceinline__ float uniform_f(float v) {
    // v is wave-uniform; route through readfirstlane to place it in an SGPR.
    return __int_as_float(__builtin_amdgcn_readfirstlane(__float_as_int(v)));
}

// EMPIRICAL launch_bounds 2nd-arg law (r1/r2/r7): VGPR cap ~= 256/arg. arg=4 -> cap 64;
// structure is r13-like (48 VGPR there) -> no spill expected. <=64 regs + 34.3 KB LDS
// -> 4 blocks x 8 waves = 32 waves/CU.
__global__ __launch_bounds__(NTHREADS, 4) void ssim_kernel(
    const float* __restrict__ x,
    const float* __restrict__ y,
    const float* __restrict__ win,
    float* __restrict__ out)
{
    __shared__ v2f vp[NTHREADS / 64][2][TH][LVWS];   // 8 wave-private slices, 34,304 B total
    __shared__ float w1s[KS];
    __shared__ float wsum[NTHREADS / 64];

    const int t   = threadIdx.x;
    const int l   = t & 63;                 // lane
    const int wid = t >> 6;                 // wave id 0..7

    const int sh    = blockIdx.x;           // 0..19
    const int strip = sh % NSTRIPS;         // 0..9
    const int half  = sh / NSTRIPS;         // 0..1
    const int plane = blockIdx.y;           // 0..47

    const int col_base = strip * SOUT;               // 0,54,...,486
    int gxi = col_base + l;                          // input col; strip 9 overshoots ->
    const int gx = (gxi < W) ? gxi : (W - 1);        // clamp (feeds only guarded outputs)
    const int row_lo = half * 256 + wid * WCHUNK;    // wave's first output row (max 480)

    const float* __restrict__ xp = x + (size_t)plane * (H * W);
    const float* __restrict__ yp = y + (size_t)plane * (H * W);

    // Separable taps: window = outer(g,g) => g[i] = sqrt(win[i][i])
    if (t < KS) w1s[t] = sqrtf(win[t * KS + t]);
    __syncthreads();    // once, before the loop (taps only)

    float w[KS];
#pragma unroll
    for (int k = 0; k < KS; k++) w[k] = uniform_f(w1s[k]);

    // Stage-2 mapping within the wave: r = l&3 (row), u = l>>2 (run of 4 px).
    // Runs u=0..13 produce cols 0..55 (valid < 54); u=14,15 are masked (lane_ok)
    // and clamp c0 to 40 -> duplicate ADDRESSES (LDS broadcast, free), outputs masked.
    const int r  = l & 3;
    const int u  = l >> 2;
    const bool lane_ok = (u <= 13);
    const int c0 = lane_ok ? (u << 2) : 40;  // reads c0..c0+13 <= 65 < 67
    const float c1 = 1e-4f;   // (0.01)^2
    const float c2 = 9e-4f;   // (0.03)^2
    float acc = 0.f;

    // Per-wave private slice
    v2f (* __restrict__ sl)[TH][LVWS] = vp[wid];

    // ---- Prime the register ring: rows row_lo..row_lo+13 (max 493, in range) ----
    float rx[IROWS], ry[IROWS];
#pragma unroll
    for (int j = 0; j < IROWS; j++) {
        const int gy = row_lo + j;
        rx[j] = xp[gy * W + gx];
        ry[j] = yp[gy * W + gx];
    }

    for (int it = 0; it < NITER; ++it) {
        const int gy0 = row_lo + it * TH;

        // ---- Stage 1: vertical 11-tap conv, packed: A={mu_x,mu_y}, B={pss,pxy} ----
        v2f A[TH], B[TH];
#pragma unroll
        for (int q = 0; q < TH; q++) { A[q] = (v2f){0.f, 0.f}; B[q] = (v2f){0.f, 0.f}; }

#pragma unroll
        for (int j = 0; j < IROWS; j++) {
            const float xv = rx[j], yv = ry[j];
            const v2f d0 = {xv, yv};
            const v2f d1 = {xv * xv + yv * yv, xv * yv};
#pragma unroll
            for (int q = 0; q < TH; q++) {
                if (j - q >= 0 && j - q < KS) {    // constant-folds after unroll
                    const float wk = w[j - q];
                    A[q] += wk * d0;               // v_pk_fma_f32
                    B[q] += wk * d1;               // v_pk_fma_f32
                }
            }
        }

        // ---- Write to the wave-private slice. NO BARRIER: same-wave LDS ops are
        // ordered; the dependent reads below get compiler-inserted lgkmcnt waits. ----
#pragma unroll
        for (int q = 0; q < TH; q++) {      // lane==col -> b64 writes, 4 dwords/bank = optimal
            sl[0][q][l] = A[q];
            sl[1][q][l] = B[q];
        }

        // ---- Slide the ring + prefetch 4 new rows per image (8 loads) ----
        // First use is NEXT iteration's vconv -> HBM latency hides under stage 2.
        if (it + 1 < NITER) {
#pragma unroll
            for (int j = 0; j < IROWS - TH; j++) {
                rx[j] = rx[j + TH];
                ry[j] = ry[j + TH];
            }
#pragma unroll
            for (int j = 0; j < TH; j++) {
                int gy = gy0 + IROWS + j;            // rows gy0+14..gy0+17 (max 525)
                gy = (gy < H - 1) ? gy : (H - 1);    // clamp feeds only guarded rows
                rx[IROWS - TH + j] = xp[gy * W + gx];
                ry[IROWS - TH + j] = yp[gy * W + gx];
            }
        }

        // ---- Stage 2: horizontal 11-tap conv (streaming) + SSIM, from own slice ----
        // Read banks: (6r + 8u + 2k) mod 32 -> 16 distinct even bases x 4 lanes
        // = 4 dwords/bank = b64 minimum (same measured-optimal class as r13).
        v2f M0[TH], M1[TH];
#pragma unroll
        for (int p = 0; p < TH; p++) { M0[p] = (v2f){0.f, 0.f}; M1[p] = (v2f){0.f, 0.f}; }

#pragma unroll
        for (int k = 0; k < IROWS; k++) {
            const v2f p0 = sl[0][r][c0 + k];     // aligned ds_read_b64
            const v2f p1 = sl[1][r][c0 + k];
#pragma unroll
            for (int p = 0; p < TH; p++) {
                if (k - p >= 0 && k - p < KS) {   // constant-folds after unroll
                    const float wk = w[k - p];
                    M0[p] += wk * p0;             // v_pk_fma_f32
                    M1[p] += wk * p1;             // v_pk_fma_f32
                }
            }
        }

        const int grow = gy0 + r;
#pragma unroll
        for (int p = 0; p < TH; p++) {
            const int lc = c0 + p;
            if (lane_ok && grow < OH && lc < SOUT && (col_base + lc) < OW) {
                const float mux = M0[p][0], muy = M0[p][1];
                const float mxy = mux * muy;
                const float m2  = mux * mux + muy * muy;
                const float sss = M1[p][0] - m2;        // sigma_x^2 + sigma_y^2
                const float sxy = M1[p][1] - mxy;
                const float num = (2.f * sxy + c2) * (2.f * mxy + c1);
                const float den = (sss + c2) * (m2 + c1);
                acc += num * __builtin_amdgcn_rcpf(den);
            }
        }
    }

    // ---- Reduction: wave shuffle -> cross-wave LDS -> one atomic/block ----
#pragma unroll
    for (int off = 32; off > 0; off >>= 1)
        acc += __shfl_down(acc, off, 64);

    if (l == 0) wsum[wid] = acc;
    __syncthreads();    // single end-of-kernel barrier
    if (t == 0) {
        float s = 0.f;
#pragma unroll
        for (int i = 0; i < NTHREADS / 64; i++) s += wsum[i];
        atomicAdd(out, s * (1.0f / (float)TOTAL_OUT));
    }
}

extern "C" void kernel_launch(void* const* d_in, const int* in_sizes, int n_in,
                              void* d_out, int out_size, void* d_ws, size_t ws_size,
                              hipStream_t stream)
{
    const float* x   = (const float*)d_in[0];
    const float* y   = (const float*)d_in[1];
    const float* win = (const float*)d_in[2];
    float* out = (float*)d_out;

    zero_out_kernel<<<1, 1, 0, stream>>>(out);

    // (10 strips x 2 row-halves, 48 planes) = 960 blocks ~= 4/CU, single round.
    // Waves are fully independent: no main-loop barriers anywhere on the chip.
    dim3 grid(NSTRIPS * 2, NPLANES);
    ssim_kernel<<<grid, NTHREADS, 0, stream>>>(x, y, win, out);
}